// Round 13
// baseline (407.148 us; speedup 1.0000x reference)
//
#include <hip/hip_runtime.h>

typedef unsigned short u16;
typedef __attribute__((ext_vector_type(8))) short bf16x8;
typedef __attribute__((ext_vector_type(8))) unsigned short u16x8;
typedef __attribute__((ext_vector_type(4))) float f32x4;

#define N_NODES 10000
#define E_EDGES 160000
#define CX_N 2560000
#define W_N  65536
#define WB_N 4194304
// big canon total = CX_N + 4*W_N + WB_N = 7016448 elems = 877056 x8 = 3426 blocks
#define CANON_BIG_BLOCKS 3426
#define HIST_BLOCKS 79          // 79*2048 = 161792 >= E_EDGES

__device__ __forceinline__ float b2f(u16 u) {
  union { unsigned i; float f; } c; c.i = ((unsigned)u) << 16; return c.f;
}
__device__ __forceinline__ u16 f2b(float f) {
  union { float f; unsigned i; } c; c.f = f;
  unsigned i = c.i;
  return (u16)((i + 0x7FFFu + ((i >> 16) & 1u)) >> 16);  // RNE
}

// ---------------------------------------------------------------------------
// Dtype detection (bf16 vs f32 inputs), same as R2-verified.
// ---------------------------------------------------------------------------
__global__ void detect_kernel(const unsigned* __restrict__ w, int* __restrict__ flag) {
  int t = threadIdx.x;  // 64 threads
  int cnt = 0;
  for (int i = t; i < 1024; i += 64) {
    unsigned e = (w[i] >> 7) & 0xFF;
    cnt += (e >= 100 && e <= 145) ? 1 : 0;
  }
  for (int o = 32; o; o >>= 1) cnt += __shfl_xor(cnt, o);
  if (t == 0) *flag = (cnt >= 512) ? 1 : 0;
}

// ---------------------------------------------------------------------------
// canon_all (R13): ONE launch replaces 4 canon launches + hist.
//  blocks [0, 3426): big tensors (cx|cwc|cw1|cw2|cw4|cwB — dst contiguous),
//    8 elems/thread, vectorized loads/stores.
//  block 3426: the 7 small tensors (scalar).
//  blocks [3427, 3427+79): edge histogram (8 edges/thread).
// ---------------------------------------------------------------------------
__global__ void canon_all_kernel(const void* sx, const void* swc, const void* sw1,
                                 const void* sw2, const void* sw4, const void* swB,
                                 const void* sbc, const void* sb1, const void* sb2,
                                 const void* sb4, const void* sw3, const void* sbB,
                                 const void* sb3,
                                 u16* __restrict__ dstBase,   // = cx (contiguous run)
                                 u16* cbc, u16* cb1, u16* cb2, u16* cb4,
                                 u16* cw3, u16* cbB, u16* cb3,
                                 const int* __restrict__ ei, int* __restrict__ count,
                                 const int* __restrict__ flag) {
  int b = blockIdx.x;
  int f = *flag;
  if (b < CANON_BIG_BLOCKS) {
    long e = ((long)b * 256 + threadIdx.x) * 8;   // elem offset (8-aligned)
    const void* src; long so;
    if (e < CX_N)                { src = sx;  so = e; }
    else if (e < CX_N + W_N)     { src = swc; so = e - CX_N; }
    else if (e < CX_N + 2 * W_N) { src = sw1; so = e - (CX_N + W_N); }
    else if (e < CX_N + 3 * W_N) { src = sw2; so = e - (CX_N + 2 * W_N); }
    else if (e < CX_N + 4 * W_N) { src = sw4; so = e - (CX_N + 3 * W_N); }
    else                         { src = swB; so = e - (CX_N + 4 * W_N); }
    if (f) {
      u16x8 v = *((const u16x8*)((const u16*)src + so));
      *(u16x8*)(dstBase + e) = v;
    } else {
      const float* fp = (const float*)src + so;
      float4 a = *(const float4*)fp;
      float4 c = *(const float4*)(fp + 4);
      u16x8 o;
      o[0] = f2b(a.x); o[1] = f2b(a.y); o[2] = f2b(a.z); o[3] = f2b(a.w);
      o[4] = f2b(c.x); o[5] = f2b(c.y); o[6] = f2b(c.z); o[7] = f2b(c.w);
      *(u16x8*)(dstBase + e) = o;
    }
  } else if (b == CANON_BIG_BLOCKS) {
    int t = threadIdx.x;
    const void* srcs[7] = {sbc, sb1, sb2, sb4, sw3, sbB, sb3};
    u16* dsts[7] = {cbc, cb1, cb2, cb4, cw3, cbB, cb3};
    const int ns[7] = {256, 256, 256, 256, 256, 64, 1};
#pragma unroll
    for (int k = 0; k < 7; ++k) {
      if (t < ns[k]) {
        if (f) dsts[k][t] = ((const u16*)srcs[k])[t];
        else   dsts[k][t] = f2b(((const float*)srcs[k])[t]);
      }
    }
  } else {
    int base = (b - CANON_BIG_BLOCKS - 1) * 2048 + threadIdx.x * 8;
#pragma unroll
    for (int k = 0; k < 8; ++k) {
      int i = base + k;
      if (i < E_EDGES) atomicAdd(&count[ei[E_EDGES + i]], 1);
    }
  }
}

// ---------------------------------------------------------------------------
// GEMM core (m97-style, R5/R12-verified): 128x128 tile, BK=64, 4 waves,
// global_load_lds 16B + XOR chunk swizzle (0 bank conflicts).
// ---------------------------------------------------------------------------
__device__ __forceinline__ void stage_async(const u16* __restrict__ src, int stride,
                                            int row0, int maxRow, int k0,
                                            u16* lds, int w, int lane) {
  int rsel = lane >> 3;
  int gch = (lane & 7) ^ rsel;
#pragma unroll
  for (int i = 0; i < 4; ++i) {
    int rb = (w * 4 + i) * 8;
    int grow = row0 + rb + rsel;
    grow = grow > maxRow ? maxRow : grow;
    const u16* gp = src + (size_t)grow * stride + k0 + gch * 8;
    u16* lp = lds + rb * 64;
    __builtin_amdgcn_global_load_lds(
        (const __attribute__((address_space(1))) void*)gp,
        (__attribute__((address_space(3))) void*)lp, 16, 0, 0);
  }
}

__device__ __forceinline__ void mma_tile(const u16* lA, const u16* lB,
                                         f32x4 acc[4][4], int wr, int wc, int lane) {
#pragma unroll
  for (int ks = 0; ks < 2; ++ks) {
    bf16x8 af[4], bfr[4];
    int g = ks * 4 + (lane >> 4);
#pragma unroll
    for (int t = 0; t < 4; ++t) {
      int rowA = wr * 64 + t * 16 + (lane & 15);
      af[t] = *(const bf16x8*)(lA + rowA * 64 + ((g ^ (rowA & 7)) * 8));
      int rowB = wc * 64 + t * 16 + (lane & 15);
      bfr[t] = *(const bf16x8*)(lB + rowB * 64 + ((g ^ (rowB & 7)) * 8));
    }
#pragma unroll
    for (int ti = 0; ti < 4; ++ti)
#pragma unroll
      for (int tj = 0; tj < 4; ++tj)
        acc[ti][tj] = __builtin_amdgcn_mfma_f32_16x16x32_bf16(af[ti], bfr[tj],
                                                              acc[ti][tj], 0, 0, 0);
  }
}

template <bool RELU, bool F32OUT>
__global__ __launch_bounds__(256, 2)
void gemm_kernel(const u16* __restrict__ A, const u16* __restrict__ B,
                 const u16* __restrict__ bias, float* __restrict__ outF,
                 u16* __restrict__ outB, int NN, int J, int K) {
  __shared__ u16 lA[128 * 64];
  __shared__ u16 lB[128 * 64];
  int lane = threadIdx.x & 63;
  int w = threadIdx.x >> 6;
  int wr = w >> 1, wc = w & 1;
  int n0 = blockIdx.y * 128;
  int j0 = blockIdx.x * 128;
  f32x4 acc[4][4];
#pragma unroll
  for (int i = 0; i < 4; ++i)
#pragma unroll
    for (int j = 0; j < 4; ++j) acc[i][j] = (f32x4){0.f, 0.f, 0.f, 0.f};

  for (int kt = 0; kt < K; kt += 64) {
    stage_async(A, K, n0, NN - 1, kt, lA, w, lane);
    stage_async(B, K, j0, J - 1, kt, lB, w, lane);
    __syncthreads();
    mma_tile(lA, lB, acc, wr, wc, lane);
    __syncthreads();
  }

#pragma unroll
  for (int ti = 0; ti < 4; ++ti)
#pragma unroll
    for (int tj = 0; tj < 4; ++tj) {
      int col = j0 + wc * 64 + tj * 16 + (lane & 15);
      float bv = bias ? b2f(bias[col]) : 0.0f;
#pragma unroll
      for (int r = 0; r < 4; ++r) {
        int row = n0 + wr * 64 + ti * 16 + ((lane >> 4) << 2) + r;
        if (row < NN) {
          float v = acc[ti][tj][r] + bv;
          if (RELU) v = fmaxf(v, 0.0f);
          if (F32OUT) outF[(size_t)row * J + col] = v;
          else        outB[(size_t)row * J + col] = f2b(v);
        }
      }
    }
}

// ---------------------------------------------------------------------------
// Fused lin2+lin3+lin4 (R10-verified).
// ---------------------------------------------------------------------------
__global__ __launch_bounds__(256, 2)
void gemm_fused234_kernel(const u16* __restrict__ A, const u16* __restrict__ B,
                          const u16* __restrict__ bias, const u16* __restrict__ w3,
                          float* __restrict__ out1acc, u16* __restrict__ x2v, int NN) {
  __shared__ u16 lA[128 * 64];
  __shared__ u16 lB[128 * 64];
  int lane = threadIdx.x & 63;
  int w = threadIdx.x >> 6;
  int wr = w >> 1, wc = w & 1;
  int n0 = blockIdx.y * 128;
  int j0 = blockIdx.x * 128;
  f32x4 acc[4][4];
#pragma unroll
  for (int i = 0; i < 4; ++i)
#pragma unroll
    for (int j = 0; j < 4; ++j) acc[i][j] = (f32x4){0.f, 0.f, 0.f, 0.f};

  for (int kt = 0; kt < 256; kt += 64) {
    stage_async(A, 256, n0, NN - 1, kt, lA, w, lane);
    stage_async(B, 256, j0, 511, kt, lB, w, lane);
    __syncthreads();
    mma_tile(lA, lB, acc, wr, wc, lane);
    __syncthreads();
  }

  if (j0 < 256) {
    float part[4][4];
#pragma unroll
    for (int ti = 0; ti < 4; ++ti)
#pragma unroll
      for (int r = 0; r < 4; ++r) part[ti][r] = 0.0f;
#pragma unroll
    for (int ti = 0; ti < 4; ++ti)
#pragma unroll
      for (int tj = 0; tj < 4; ++tj) {
        int col = j0 + wc * 64 + tj * 16 + (lane & 15);
        float bv = b2f(bias[col]);
        float wv = b2f(w3[col]);
#pragma unroll
        for (int r = 0; r < 4; ++r) {
          float v = fmaxf(acc[ti][tj][r] + bv, 0.0f);
          part[ti][r] += v * wv;
        }
      }
#pragma unroll
    for (int ti = 0; ti < 4; ++ti)
#pragma unroll
      for (int r = 0; r < 4; ++r) {
        float s = part[ti][r];
        s += __shfl_xor(s, 1);
        s += __shfl_xor(s, 2);
        s += __shfl_xor(s, 4);
        s += __shfl_xor(s, 8);
        if ((lane & 15) == 0) {
          int row = n0 + wr * 64 + ti * 16 + ((lane >> 4) << 2) + r;
          if (row < NN) unsafeAtomicAdd(&out1acc[row], s);
        }
      }
  } else {
#pragma unroll
    for (int ti = 0; ti < 4; ++ti)
#pragma unroll
      for (int tj = 0; tj < 4; ++tj) {
        int col = j0 + wc * 64 + tj * 16 + (lane & 15);
        float bv = b2f(bias[col]);
#pragma unroll
        for (int r = 0; r < 4; ++r) {
          int row = n0 + wr * 64 + ti * 16 + ((lane >> 4) << 2) + r;
          if (row < NN) {
            float v = fmaxf(acc[ti][tj][r] + bv, 0.0f);
            x2v[(size_t)row * 256 + (col - 256)] = f2b(v);
          }
        }
      }
  }
}

// ---------------------------------------------------------------------------
// Bilinear (R9 kernel; R13 change: __launch_bounds__(256,3) to force 3-wave/EU
// regalloc — current use 104 VGPR + 64 AGPR ≈ 168, budget for 3 waves is 170).
// ---------------------------------------------------------------------------
__global__ __launch_bounds__(256, 3)
void bilinear_kernel(const u16* __restrict__ x2v, const u16* __restrict__ W,
                     float* __restrict__ out2acc, int NN) {
  __shared__ u16 lA[128 * 64];
  __shared__ u16 lB[128 * 64];
  int lane = threadIdx.x & 63;
  int w = threadIdx.x >> 6;
  int wr = w >> 1, wc = w & 1;
  int n0 = blockIdx.y * 128;
  int rm0 = blockIdx.x * 128;
  int m0g = rm0 & 255;
  int xv_kt = (m0g >> 6) + wc;
  f32x4 acc[4][4];
#pragma unroll
  for (int i = 0; i < 4; ++i)
#pragma unroll
    for (int j = 0; j < 4; ++j) acc[i][j] = (f32x4){0.f, 0.f, 0.f, 0.f};

  u16 xvr[4][16];

#pragma unroll
  for (int kt4 = 0; kt4 < 4; ++kt4) {
    stage_async(x2v, 256, n0, NN - 1, kt4 * 64, lA, w, lane);
    stage_async(W, 256, rm0, 16383, kt4 * 64, lB, w, lane);
    __syncthreads();
    mma_tile(lA, lB, acc, wr, wc, lane);
    if (kt4 == xv_kt) {
#pragma unroll
      for (int tj = 0; tj < 4; ++tj) {
        int kl = tj * 16 + (lane & 15);
        int ch = kl >> 3, off = kl & 7;
#pragma unroll
        for (int ti = 0; ti < 4; ++ti)
#pragma unroll
          for (int r = 0; r < 4; ++r) {
            int rowl = wr * 64 + ti * 16 + ((lane >> 4) << 2) + r;
            xvr[tj][ti * 4 + r] = lA[rowl * 64 + ((ch ^ (rowl & 7)) * 8) + off];
          }
      }
    }
    __syncthreads();
  }

  int region = rm0 >> 8;
  float rowsum[4][4];
#pragma unroll
  for (int ti = 0; ti < 4; ++ti)
#pragma unroll
    for (int r = 0; r < 4; ++r) rowsum[ti][r] = 0.0f;

#pragma unroll
  for (int ti = 0; ti < 4; ++ti)
#pragma unroll
    for (int tj = 0; tj < 4; ++tj)
#pragma unroll
      for (int r = 0; r < 4; ++r)
        rowsum[ti][r] += acc[ti][tj][r] * b2f(xvr[tj][ti * 4 + r]);

#pragma unroll
  for (int ti = 0; ti < 4; ++ti)
#pragma unroll
    for (int r = 0; r < 4; ++r) {
      float s = rowsum[ti][r];
      s += __shfl_xor(s, 1);
      s += __shfl_xor(s, 2);
      s += __shfl_xor(s, 4);
      s += __shfl_xor(s, 8);
      if ((lane & 15) == 0) {
        int rowl = wr * 64 + ti * 16 + ((lane >> 4) << 2) + r;
        int n = n0 + rowl;
        if (n < NN) unsafeAtomicAdd(&out2acc[(size_t)n * 64 + region], s);
      }
    }
}

// --------------------- edge sort (scan/place) + gather ----------------------
__global__ void scan_kernel(const int* __restrict__ count, int* __restrict__ start,
                            int* __restrict__ cursor, float* __restrict__ dinv) {
  __shared__ int wsum[16];
  __shared__ int carry_s;
  int t = threadIdx.x;          // 1024 threads = 16 waves
  int wv = t >> 6, ln = t & 63;
  if (t == 0) carry_s = 0;
  __syncthreads();
  for (int base = 0; base < N_NODES; base += 1024) {
    int i = base + t;
    int v = (i < N_NODES) ? count[i] : 0;
    int s = v;
#pragma unroll
    for (int o = 1; o < 64; o <<= 1) {
      int u = __shfl_up(s, o);
      if (ln >= o) s += u;
    }
    if (ln == 63) wsum[wv] = s;
    __syncthreads();
    if (wv == 0) {
      int x = (ln < 16) ? wsum[ln] : 0;
#pragma unroll
      for (int o = 1; o < 16; o <<= 1) {
        int u = __shfl_up(x, o);
        if (ln >= o) x += u;
      }
      if (ln < 16) wsum[ln] = x;
    }
    __syncthreads();
    int excl = s - v + (wv ? wsum[wv - 1] : 0) + carry_s;
    if (i < N_NODES) {
      start[i] = excl;
      cursor[i] = excl;
      dinv[i] = rsqrtf(1.0f + (float)v);
    }
    __syncthreads();
    if (t == 0) carry_s += wsum[15];
    __syncthreads();
  }
}

__global__ void place_kernel(const int* __restrict__ ei, int* __restrict__ cursor,
                             int* __restrict__ order) {
  int i = blockIdx.x * 256 + threadIdx.x;
  if (i >= E_EDGES) return;
  int d = ei[E_EDGES + i];
  int pos = atomicAdd(&cursor[d], 1);
  order[pos] = i;
}

__global__ void gather_kernel(const int* __restrict__ ei, const int* __restrict__ order,
                              const int* __restrict__ start, const int* __restrict__ count,
                              const float* __restrict__ dinv, const float* __restrict__ xw,
                              const u16* __restrict__ conv_b, const u16* __restrict__ x,
                              u16* __restrict__ x0) {
  int node = (blockIdx.x * blockDim.x + threadIdx.x) >> 6;
  int lane = threadIdx.x & 63;
  if (node >= N_NODES) return;
  int s0 = start[node], cnt = count[node];
  float dn = dinv[node];
  float ax = 0.f, ay = 0.f, az = 0.f, aw = 0.f;
  for (int base = 0; base < cnt; base += 64) {
    int rem = cnt - base;
    int m = rem < 64 ? rem : 64;
    int eid = (lane < m) ? order[s0 + base + lane] : 0;
    int s = (lane < m) ? ei[eid] : 0;
    float nrm = (lane < m) ? dinv[s] * dn : 0.f;
    for (int j = 0; j < m; ++j) {
      int sj = __shfl(s, j);
      float nj = __shfl(nrm, j);
      float4 v = *((const float4*)(xw + (size_t)sj * 256) + lane);
      ax += nj * v.x; ay += nj * v.y; az += nj * v.z; aw += nj * v.w;
    }
  }
  float4 sv = *((const float4*)(xw + (size_t)node * 256) + lane);
  float slw = dn * dn;
  const u16* bb = conv_b + lane * 4;
  const u16* xr = x + (size_t)node * 256 + lane * 4;
  u16 o[4];
  float vals[4] = {ax + slw * sv.x, ay + slw * sv.y, az + slw * sv.z, aw + slw * sv.w};
#pragma unroll
  for (int j = 0; j < 4; ++j) {
    float v = vals[j] + b2f(bb[j]);
    v = fmaxf(v, 0.0f) + b2f(xr[j]);
    o[j] = f2b(v);
  }
  *((ushort4*)(x0 + (size_t)node * 256) + lane) = make_ushort4(o[0], o[1], o[2], o[3]);
}

// ------------------------------- final output -------------------------------
__global__ void out_final_kernel(const float* __restrict__ out1acc,
                                 const float* __restrict__ out2acc,
                                 const u16* __restrict__ b3, const u16* __restrict__ bb,
                                 void* __restrict__ dout, const int* __restrict__ flag) {
  int idx = blockIdx.x * 256 + threadIdx.x;
  int f = *flag;
  if (idx < N_NODES) {
    float v = out1acc[idx] + b2f(b3[0]);
    if (f) ((u16*)dout)[idx] = f2b(v);
    else   ((float*)dout)[idx] = v;
  } else if (idx < N_NODES + N_NODES * 64) {
    int k = idx - N_NODES;
    float v = out2acc[k] + b2f(bb[k & 63]);
    if (f) ((u16*)dout)[idx] = f2b(v);
    else   ((float*)dout)[idx] = v;
  }
}

// ----------------------------------------------------------------------------
extern "C" void kernel_launch(void* const* d_in, const int* in_sizes, int n_in,
                              void* d_out, int out_size, void* d_ws, size_t ws_size,
                              hipStream_t stream) {
  const int* ei = (const int*)d_in[1];

  float* ws      = (float*)d_ws;
  float* xw      = ws;                          // [N,256] f32
  int*   count   = (int*)(xw + N_NODES * 256);  // [N]
  int*   start   = count + 10240;               // [N]
  int*   cursor  = start + 10240;               // [N]
  int*   order   = cursor + 10240;              // [E]
  float* dinv    = (float*)(order + E_EDGES);   // [N]
  float* out1acc = dinv + 10240;                // [N] (padded 10240)
  float* out2acc = out1acc + 10240;             // [N,64] (adjacent: one memset)
  u16* x0  = (u16*)(out2acc + N_NODES * 64);    // [N,256] bf16
  u16* x0m = x0 + N_NODES * 256;
  u16* x2v = x0m + N_NODES * 256;
  // canonical bf16 inputs — cx..cwB CONTIGUOUS (canon_all relies on this)
  u16* cx  = x2v + N_NODES * 256;
  u16* cwc = cx + CX_N;
  u16* cw1 = cwc + W_N;
  u16* cw2 = cw1 + W_N;                         // cw2, cw4 contiguous = [512,256]
  u16* cw4 = cw2 + W_N;
  u16* cwB = cw4 + W_N;
  u16* cbc = cwB + WB_N;
  u16* cb1 = cbc + 256;
  u16* cb2 = cb1 + 256;                         // cb2, cb4 contiguous = [512]
  u16* cb4 = cb2 + 256;
  u16* cw3 = cb4 + 256;
  u16* cbB = cw3 + 256;
  u16* cb3 = cbB + 64;
  int* flag = (int*)(cb3 + 16);

  hipMemsetAsync(count, 0, N_NODES * sizeof(int), stream);
  hipMemsetAsync(out1acc, 0, (10240 + (size_t)N_NODES * 64) * sizeof(float), stream);

  detect_kernel<<<1, 64, 0, stream>>>((const unsigned*)d_in[0], flag);

  canon_all_kernel<<<CANON_BIG_BLOCKS + 1 + HIST_BLOCKS, 256, 0, stream>>>(
      d_in[0], d_in[2], d_in[4], d_in[6], d_in[10], d_in[12],
      d_in[3], d_in[5], d_in[7], d_in[11], d_in[8], d_in[13], d_in[9],
      cx, cbc, cb1, cb2, cb4, cw3, cbB, cb3,
      ei, count, flag);

  scan_kernel<<<1, 1024, 0, stream>>>(count, start, cursor, dinv);
  place_kernel<<<(E_EDGES + 255) / 256, 256, 0, stream>>>(ei, cursor, order);

  gemm_kernel<false, true><<<dim3(2, 79), 256, 0, stream>>>(
      cx, cwc, nullptr, xw, nullptr, N_NODES, 256, 256);

  gather_kernel<<<(N_NODES * 64 + 255) / 256, 256, 0, stream>>>(
      ei, order, start, count, dinv, xw, cbc, cx, x0);

  gemm_kernel<true, false><<<dim3(2, 79), 256, 0, stream>>>(
      x0, cw1, cb1, nullptr, x0m, N_NODES, 256, 256);

  gemm_fused234_kernel<<<dim3(4, 79), 256, 0, stream>>>(
      x0m, cw2, cb2, cw3, out1acc, x2v, N_NODES);

  bilinear_kernel<<<dim3(128, 79), 256, 0, stream>>>(x2v, cwB, out2acc, N_NODES);

  out_final_kernel<<<(N_NODES * 65 + 255) / 256, 256, 0, stream>>>(
      out1acc, out2acc, cb3, cbB, d_out, flag);
}

// Round 14
// 388.491 us; speedup vs baseline: 1.0480x; 1.0480x over previous
//
#include <hip/hip_runtime.h>

typedef unsigned short u16;
typedef __attribute__((ext_vector_type(8))) short bf16x8;
typedef __attribute__((ext_vector_type(8))) unsigned short u16x8;
typedef __attribute__((ext_vector_type(4))) float f32x4;

#define N_NODES 10000
#define E_EDGES 160000
#define CX_N 2560000
#define W_N  65536
#define WB_N 4194304
// big canon total = CX_N + 4*W_N + WB_N = 7016448 elems = 877056 x8 = 3426 blocks
#define CANON_BIG_BLOCKS 3426
#define HIST_BLOCKS 79          // 79*2048 = 161792 >= E_EDGES

__device__ __forceinline__ float b2f(u16 u) {
  union { unsigned i; float f; } c; c.i = ((unsigned)u) << 16; return c.f;
}
__device__ __forceinline__ u16 f2b(float f) {
  union { float f; unsigned i; } c; c.f = f;
  unsigned i = c.i;
  return (u16)((i + 0x7FFFu + ((i >> 16) & 1u)) >> 16);  // RNE
}

// ---------------------------------------------------------------------------
// Dtype detection (bf16 vs f32 inputs), R2-verified.
// ---------------------------------------------------------------------------
__global__ void detect_kernel(const unsigned* __restrict__ w, int* __restrict__ flag) {
  int t = threadIdx.x;  // 64 threads
  int cnt = 0;
  for (int i = t; i < 1024; i += 64) {
    unsigned e = (w[i] >> 7) & 0xFF;
    cnt += (e >= 100 && e <= 145) ? 1 : 0;
  }
  for (int o = 32; o; o >>= 1) cnt += __shfl_xor(cnt, o);
  if (t == 0) *flag = (cnt >= 512) ? 1 : 0;
}

// ---------------------------------------------------------------------------
// canon_all (R13-verified, ~7 µs tail win): ONE launch = 4 canons + hist.
// ---------------------------------------------------------------------------
__global__ void canon_all_kernel(const void* sx, const void* swc, const void* sw1,
                                 const void* sw2, const void* sw4, const void* swB,
                                 const void* sbc, const void* sb1, const void* sb2,
                                 const void* sb4, const void* sw3, const void* sbB,
                                 const void* sb3,
                                 u16* __restrict__ dstBase,   // = cx (contiguous run)
                                 u16* cbc, u16* cb1, u16* cb2, u16* cb4,
                                 u16* cw3, u16* cbB, u16* cb3,
                                 const int* __restrict__ ei, int* __restrict__ count,
                                 const int* __restrict__ flag) {
  int b = blockIdx.x;
  int f = *flag;
  if (b < CANON_BIG_BLOCKS) {
    long e = ((long)b * 256 + threadIdx.x) * 8;   // elem offset (8-aligned)
    const void* src; long so;
    if (e < CX_N)                { src = sx;  so = e; }
    else if (e < CX_N + W_N)     { src = swc; so = e - CX_N; }
    else if (e < CX_N + 2 * W_N) { src = sw1; so = e - (CX_N + W_N); }
    else if (e < CX_N + 3 * W_N) { src = sw2; so = e - (CX_N + 2 * W_N); }
    else if (e < CX_N + 4 * W_N) { src = sw4; so = e - (CX_N + 3 * W_N); }
    else                         { src = swB; so = e - (CX_N + 4 * W_N); }
    if (f) {
      u16x8 v = *((const u16x8*)((const u16*)src + so));
      *(u16x8*)(dstBase + e) = v;
    } else {
      const float* fp = (const float*)src + so;
      float4 a = *(const float4*)fp;
      float4 c = *(const float4*)(fp + 4);
      u16x8 o;
      o[0] = f2b(a.x); o[1] = f2b(a.y); o[2] = f2b(a.z); o[3] = f2b(a.w);
      o[4] = f2b(c.x); o[5] = f2b(c.y); o[6] = f2b(c.z); o[7] = f2b(c.w);
      *(u16x8*)(dstBase + e) = o;
    }
  } else if (b == CANON_BIG_BLOCKS) {
    int t = threadIdx.x;
    const void* srcs[7] = {sbc, sb1, sb2, sb4, sw3, sbB, sb3};
    u16* dsts[7] = {cbc, cb1, cb2, cb4, cw3, cbB, cb3};
    const int ns[7] = {256, 256, 256, 256, 256, 64, 1};
#pragma unroll
    for (int k = 0; k < 7; ++k) {
      if (t < ns[k]) {
        if (f) dsts[k][t] = ((const u16*)srcs[k])[t];
        else   dsts[k][t] = f2b(((const float*)srcs[k])[t]);
      }
    }
  } else {
    int base = (b - CANON_BIG_BLOCKS - 1) * 2048 + threadIdx.x * 8;
#pragma unroll
    for (int k = 0; k < 8; ++k) {
      int i = base + k;
      if (i < E_EDGES) atomicAdd(&count[ei[E_EDGES + i]], 1);
    }
  }
}

// ---------------------------------------------------------------------------
// GEMM core (m97-style, R5/R12-verified): 128x128 tile, BK=64, 4 waves,
// global_load_lds 16B + XOR chunk swizzle (0 bank conflicts).
// ---------------------------------------------------------------------------
__device__ __forceinline__ void stage_async(const u16* __restrict__ src, int stride,
                                            int row0, int maxRow, int k0,
                                            u16* lds, int w, int lane) {
  int rsel = lane >> 3;
  int gch = (lane & 7) ^ rsel;
#pragma unroll
  for (int i = 0; i < 4; ++i) {
    int rb = (w * 4 + i) * 8;
    int grow = row0 + rb + rsel;
    grow = grow > maxRow ? maxRow : grow;
    const u16* gp = src + (size_t)grow * stride + k0 + gch * 8;
    u16* lp = lds + rb * 64;
    __builtin_amdgcn_global_load_lds(
        (const __attribute__((address_space(1))) void*)gp,
        (__attribute__((address_space(3))) void*)lp, 16, 0, 0);
  }
}

__device__ __forceinline__ void mma_tile(const u16* lA, const u16* lB,
                                         f32x4 acc[4][4], int wr, int wc, int lane) {
#pragma unroll
  for (int ks = 0; ks < 2; ++ks) {
    bf16x8 af[4], bfr[4];
    int g = ks * 4 + (lane >> 4);
#pragma unroll
    for (int t = 0; t < 4; ++t) {
      int rowA = wr * 64 + t * 16 + (lane & 15);
      af[t] = *(const bf16x8*)(lA + rowA * 64 + ((g ^ (rowA & 7)) * 8));
      int rowB = wc * 64 + t * 16 + (lane & 15);
      bfr[t] = *(const bf16x8*)(lB + rowB * 64 + ((g ^ (rowB & 7)) * 8));
    }
#pragma unroll
    for (int ti = 0; ti < 4; ++ti)
#pragma unroll
      for (int tj = 0; tj < 4; ++tj)
        acc[ti][tj] = __builtin_amdgcn_mfma_f32_16x16x32_bf16(af[ti], bfr[tj],
                                                              acc[ti][tj], 0, 0, 0);
  }
}

template <bool RELU, bool F32OUT>
__global__ __launch_bounds__(256, 2)
void gemm_kernel(const u16* __restrict__ A, const u16* __restrict__ B,
                 const u16* __restrict__ bias, float* __restrict__ outF,
                 u16* __restrict__ outB, int NN, int J, int K) {
  __shared__ u16 lA[128 * 64];
  __shared__ u16 lB[128 * 64];
  int lane = threadIdx.x & 63;
  int w = threadIdx.x >> 6;
  int wr = w >> 1, wc = w & 1;
  int n0 = blockIdx.y * 128;
  int j0 = blockIdx.x * 128;
  f32x4 acc[4][4];
#pragma unroll
  for (int i = 0; i < 4; ++i)
#pragma unroll
    for (int j = 0; j < 4; ++j) acc[i][j] = (f32x4){0.f, 0.f, 0.f, 0.f};

  for (int kt = 0; kt < K; kt += 64) {
    stage_async(A, K, n0, NN - 1, kt, lA, w, lane);
    stage_async(B, K, j0, J - 1, kt, lB, w, lane);
    __syncthreads();
    mma_tile(lA, lB, acc, wr, wc, lane);
    __syncthreads();
  }

#pragma unroll
  for (int ti = 0; ti < 4; ++ti)
#pragma unroll
    for (int tj = 0; tj < 4; ++tj) {
      int col = j0 + wc * 64 + tj * 16 + (lane & 15);
      float bv = bias ? b2f(bias[col]) : 0.0f;
#pragma unroll
      for (int r = 0; r < 4; ++r) {
        int row = n0 + wr * 64 + ti * 16 + ((lane >> 4) << 2) + r;
        if (row < NN) {
          float v = acc[ti][tj][r] + bv;
          if (RELU) v = fmaxf(v, 0.0f);
          if (F32OUT) outF[(size_t)row * J + col] = v;
          else        outB[(size_t)row * J + col] = f2b(v);
        }
      }
    }
}

// ---------------------------------------------------------------------------
// Fused lin2+lin3+lin4 (R10-verified).
// ---------------------------------------------------------------------------
__global__ __launch_bounds__(256, 2)
void gemm_fused234_kernel(const u16* __restrict__ A, const u16* __restrict__ B,
                          const u16* __restrict__ bias, const u16* __restrict__ w3,
                          float* __restrict__ out1acc, u16* __restrict__ x2v, int NN) {
  __shared__ u16 lA[128 * 64];
  __shared__ u16 lB[128 * 64];
  int lane = threadIdx.x & 63;
  int w = threadIdx.x >> 6;
  int wr = w >> 1, wc = w & 1;
  int n0 = blockIdx.y * 128;
  int j0 = blockIdx.x * 128;
  f32x4 acc[4][4];
#pragma unroll
  for (int i = 0; i < 4; ++i)
#pragma unroll
    for (int j = 0; j < 4; ++j) acc[i][j] = (f32x4){0.f, 0.f, 0.f, 0.f};

  for (int kt = 0; kt < 256; kt += 64) {
    stage_async(A, 256, n0, NN - 1, kt, lA, w, lane);
    stage_async(B, 256, j0, 511, kt, lB, w, lane);
    __syncthreads();
    mma_tile(lA, lB, acc, wr, wc, lane);
    __syncthreads();
  }

  if (j0 < 256) {
    float part[4][4];
#pragma unroll
    for (int ti = 0; ti < 4; ++ti)
#pragma unroll
      for (int r = 0; r < 4; ++r) part[ti][r] = 0.0f;
#pragma unroll
    for (int ti = 0; ti < 4; ++ti)
#pragma unroll
      for (int tj = 0; tj < 4; ++tj) {
        int col = j0 + wc * 64 + tj * 16 + (lane & 15);
        float bv = b2f(bias[col]);
        float wv = b2f(w3[col]);
#pragma unroll
        for (int r = 0; r < 4; ++r) {
          float v = fmaxf(acc[ti][tj][r] + bv, 0.0f);
          part[ti][r] += v * wv;
        }
      }
#pragma unroll
    for (int ti = 0; ti < 4; ++ti)
#pragma unroll
      for (int r = 0; r < 4; ++r) {
        float s = part[ti][r];
        s += __shfl_xor(s, 1);
        s += __shfl_xor(s, 2);
        s += __shfl_xor(s, 4);
        s += __shfl_xor(s, 8);
        if ((lane & 15) == 0) {
          int row = n0 + wr * 64 + ti * 16 + ((lane >> 4) << 2) + r;
          if (row < NN) unsafeAtomicAdd(&out1acc[row], s);
        }
      }
  } else {
#pragma unroll
    for (int ti = 0; ti < 4; ++ti)
#pragma unroll
      for (int tj = 0; tj < 4; ++tj) {
        int col = j0 + wc * 64 + tj * 16 + (lane & 15);
        float bv = b2f(bias[col]);
#pragma unroll
        for (int r = 0; r < 4; ++r) {
          int row = n0 + wr * 64 + ti * 16 + ((lane >> 4) << 2) + r;
          if (row < NN) {
            float v = fmaxf(acc[ti][tj][r] + bv, 0.0f);
            x2v[(size_t)row * 256 + (col - 256)] = f2b(v);
          }
        }
      }
  }
}

// ---------------------------------------------------------------------------
// Bilinear (R9/R12-verified, 211 µs, __launch_bounds__(256,2) — R13 showed
// forcing 3 waves/EU spills to scratch: FETCH 24->178MB, WRITE 80->444MB).
// ---------------------------------------------------------------------------
__global__ __launch_bounds__(256, 2)
void bilinear_kernel(const u16* __restrict__ x2v, const u16* __restrict__ W,
                     float* __restrict__ out2acc, int NN) {
  __shared__ u16 lA[128 * 64];
  __shared__ u16 lB[128 * 64];
  int lane = threadIdx.x & 63;
  int w = threadIdx.x >> 6;
  int wr = w >> 1, wc = w & 1;
  int n0 = blockIdx.y * 128;
  int rm0 = blockIdx.x * 128;
  int m0g = rm0 & 255;
  int xv_kt = (m0g >> 6) + wc;
  f32x4 acc[4][4];
#pragma unroll
  for (int i = 0; i < 4; ++i)
#pragma unroll
    for (int j = 0; j < 4; ++j) acc[i][j] = (f32x4){0.f, 0.f, 0.f, 0.f};

  u16 xvr[4][16];

#pragma unroll
  for (int kt4 = 0; kt4 < 4; ++kt4) {
    stage_async(x2v, 256, n0, NN - 1, kt4 * 64, lA, w, lane);
    stage_async(W, 256, rm0, 16383, kt4 * 64, lB, w, lane);
    __syncthreads();
    mma_tile(lA, lB, acc, wr, wc, lane);
    if (kt4 == xv_kt) {
#pragma unroll
      for (int tj = 0; tj < 4; ++tj) {
        int kl = tj * 16 + (lane & 15);
        int ch = kl >> 3, off = kl & 7;
#pragma unroll
        for (int ti = 0; ti < 4; ++ti)
#pragma unroll
          for (int r = 0; r < 4; ++r) {
            int rowl = wr * 64 + ti * 16 + ((lane >> 4) << 2) + r;
            xvr[tj][ti * 4 + r] = lA[rowl * 64 + ((ch ^ (rowl & 7)) * 8) + off];
          }
      }
    }
    __syncthreads();
  }

  int region = rm0 >> 8;
  float rowsum[4][4];
#pragma unroll
  for (int ti = 0; ti < 4; ++ti)
#pragma unroll
    for (int r = 0; r < 4; ++r) rowsum[ti][r] = 0.0f;

#pragma unroll
  for (int ti = 0; ti < 4; ++ti)
#pragma unroll
    for (int tj = 0; tj < 4; ++tj)
#pragma unroll
      for (int r = 0; r < 4; ++r)
        rowsum[ti][r] += acc[ti][tj][r] * b2f(xvr[tj][ti * 4 + r]);

#pragma unroll
  for (int ti = 0; ti < 4; ++ti)
#pragma unroll
    for (int r = 0; r < 4; ++r) {
      float s = rowsum[ti][r];
      s += __shfl_xor(s, 1);
      s += __shfl_xor(s, 2);
      s += __shfl_xor(s, 4);
      s += __shfl_xor(s, 8);
      if ((lane & 15) == 0) {
        int rowl = wr * 64 + ti * 16 + ((lane >> 4) << 2) + r;
        int n = n0 + rowl;
        if (n < NN) unsafeAtomicAdd(&out2acc[(size_t)n * 64 + region], s);
      }
    }
}

// --------------------- edge sort (scan/place) + gather ----------------------
__global__ void scan_kernel(const int* __restrict__ count, int* __restrict__ start,
                            int* __restrict__ cursor, float* __restrict__ dinv) {
  __shared__ int wsum[16];
  __shared__ int carry_s;
  int t = threadIdx.x;          // 1024 threads = 16 waves
  int wv = t >> 6, ln = t & 63;
  if (t == 0) carry_s = 0;
  __syncthreads();
  for (int base = 0; base < N_NODES; base += 1024) {
    int i = base + t;
    int v = (i < N_NODES) ? count[i] : 0;
    int s = v;
#pragma unroll
    for (int o = 1; o < 64; o <<= 1) {
      int u = __shfl_up(s, o);
      if (ln >= o) s += u;
    }
    if (ln == 63) wsum[wv] = s;
    __syncthreads();
    if (wv == 0) {
      int x = (ln < 16) ? wsum[ln] : 0;
#pragma unroll
      for (int o = 1; o < 16; o <<= 1) {
        int u = __shfl_up(x, o);
        if (ln >= o) x += u;
      }
      if (ln < 16) wsum[ln] = x;
    }
    __syncthreads();
    int excl = s - v + (wv ? wsum[wv - 1] : 0) + carry_s;
    if (i < N_NODES) {
      start[i] = excl;
      cursor[i] = excl;
      dinv[i] = rsqrtf(1.0f + (float)v);
    }
    __syncthreads();
    if (t == 0) carry_s += wsum[15];
    __syncthreads();
  }
}

__global__ void place_kernel(const int* __restrict__ ei, int* __restrict__ cursor,
                             int* __restrict__ order) {
  int i = blockIdx.x * 256 + threadIdx.x;
  if (i >= E_EDGES) return;
  int d = ei[E_EDGES + i];
  int pos = atomicAdd(&cursor[d], 1);
  order[pos] = i;
}

__global__ void gather_kernel(const int* __restrict__ ei, const int* __restrict__ order,
                              const int* __restrict__ start, const int* __restrict__ count,
                              const float* __restrict__ dinv, const float* __restrict__ xw,
                              const u16* __restrict__ conv_b, const u16* __restrict__ x,
                              u16* __restrict__ x0) {
  int node = (blockIdx.x * blockDim.x + threadIdx.x) >> 6;
  int lane = threadIdx.x & 63;
  if (node >= N_NODES) return;
  int s0 = start[node], cnt = count[node];
  float dn = dinv[node];
  float ax = 0.f, ay = 0.f, az = 0.f, aw = 0.f;
  for (int base = 0; base < cnt; base += 64) {
    int rem = cnt - base;
    int m = rem < 64 ? rem : 64;
    int eid = (lane < m) ? order[s0 + base + lane] : 0;
    int s = (lane < m) ? ei[eid] : 0;
    float nrm = (lane < m) ? dinv[s] * dn : 0.f;
    for (int j = 0; j < m; ++j) {
      int sj = __shfl(s, j);
      float nj = __shfl(nrm, j);
      float4 v = *((const float4*)(xw + (size_t)sj * 256) + lane);
      ax += nj * v.x; ay += nj * v.y; az += nj * v.z; aw += nj * v.w;
    }
  }
  float4 sv = *((const float4*)(xw + (size_t)node * 256) + lane);
  float slw = dn * dn;
  const u16* bb = conv_b + lane * 4;
  const u16* xr = x + (size_t)node * 256 + lane * 4;
  u16 o[4];
  float vals[4] = {ax + slw * sv.x, ay + slw * sv.y, az + slw * sv.z, aw + slw * sv.w};
#pragma unroll
  for (int j = 0; j < 4; ++j) {
    float v = vals[j] + b2f(bb[j]);
    v = fmaxf(v, 0.0f) + b2f(xr[j]);
    o[j] = f2b(v);
  }
  *((ushort4*)(x0 + (size_t)node * 256) + lane) = make_ushort4(o[0], o[1], o[2], o[3]);
}

// ------------------------------- final output -------------------------------
__global__ void out_final_kernel(const float* __restrict__ out1acc,
                                 const float* __restrict__ out2acc,
                                 const u16* __restrict__ b3, const u16* __restrict__ bb,
                                 void* __restrict__ dout, const int* __restrict__ flag) {
  int idx = blockIdx.x * 256 + threadIdx.x;
  int f = *flag;
  if (idx < N_NODES) {
    float v = out1acc[idx] + b2f(b3[0]);
    if (f) ((u16*)dout)[idx] = f2b(v);
    else   ((float*)dout)[idx] = v;
  } else if (idx < N_NODES + N_NODES * 64) {
    int k = idx - N_NODES;
    float v = out2acc[k] + b2f(bb[k & 63]);
    if (f) ((u16*)dout)[idx] = f2b(v);
    else   ((float*)dout)[idx] = v;
  }
}

// ----------------------------------------------------------------------------
extern "C" void kernel_launch(void* const* d_in, const int* in_sizes, int n_in,
                              void* d_out, int out_size, void* d_ws, size_t ws_size,
                              hipStream_t stream) {
  const int* ei = (const int*)d_in[1];

  float* ws      = (float*)d_ws;
  float* xw      = ws;                          // [N,256] f32
  int*   count   = (int*)(xw + N_NODES * 256);  // [N]
  int*   start   = count + 10240;               // [N]
  int*   cursor  = start + 10240;               // [N]
  int*   order   = cursor + 10240;              // [E]
  float* dinv    = (float*)(order + E_EDGES);   // [N]
  float* out1acc = dinv + 10240;                // [N] (padded 10240)
  float* out2acc = out1acc + 10240;             // [N,64] (adjacent: one memset)
  u16* x0  = (u16*)(out2acc + N_NODES * 64);    // [N,256] bf16
  u16* x0m = x0 + N_NODES * 256;
  u16* x2v = x0m + N_NODES * 256;
  // canonical bf16 inputs — cx..cwB CONTIGUOUS (canon_all relies on this)
  u16* cx  = x2v + N_NODES * 256;
  u16* cwc = cx + CX_N;
  u16* cw1 = cwc + W_N;
  u16* cw2 = cw1 + W_N;                         // cw2, cw4 contiguous = [512,256]
  u16* cw4 = cw2 + W_N;
  u16* cwB = cw4 + W_N;
  u16* cbc = cwB + WB_N;
  u16* cb1 = cbc + 256;
  u16* cb2 = cb1 + 256;                         // cb2, cb4 contiguous = [512]
  u16* cb4 = cb2 + 256;
  u16* cw3 = cb4 + 256;
  u16* cbB = cw3 + 256;
  u16* cb3 = cbB + 64;
  int* flag = (int*)(cb3 + 16);

  hipMemsetAsync(count, 0, N_NODES * sizeof(int), stream);
  hipMemsetAsync(out1acc, 0, (10240 + (size_t)N_NODES * 64) * sizeof(float), stream);

  detect_kernel<<<1, 64, 0, stream>>>((const unsigned*)d_in[0], flag);

  canon_all_kernel<<<CANON_BIG_BLOCKS + 1 + HIST_BLOCKS, 256, 0, stream>>>(
      d_in[0], d_in[2], d_in[4], d_in[6], d_in[10], d_in[12],
      d_in[3], d_in[5], d_in[7], d_in[11], d_in[8], d_in[13], d_in[9],
      cx, cbc, cb1, cb2, cb4, cw3, cbB, cb3,
      ei, count, flag);

  scan_kernel<<<1, 1024, 0, stream>>>(count, start, cursor, dinv);
  place_kernel<<<(E_EDGES + 255) / 256, 256, 0, stream>>>(ei, cursor, order);

  gemm_kernel<false, true><<<dim3(2, 79), 256, 0, stream>>>(
      cx, cwc, nullptr, xw, nullptr, N_NODES, 256, 256);

  gather_kernel<<<(N_NODES * 64 + 255) / 256, 256, 0, stream>>>(
      ei, order, start, count, dinv, xw, cbc, cx, x0);

  gemm_kernel<true, false><<<dim3(2, 79), 256, 0, stream>>>(
      x0, cw1, cb1, nullptr, x0m, N_NODES, 256, 256);

  gemm_fused234_kernel<<<dim3(4, 79), 256, 0, stream>>>(
      x0m, cw2, cb2, cw3, out1acc, x2v, N_NODES);

  bilinear_kernel<<<dim3(128, 79), 256, 0, stream>>>(x2v, cwB, out2acc, N_NODES);

  out_final_kernel<<<(N_NODES * 65 + 255) / 256, 256, 0, stream>>>(
      out1acc, out2acc, cb3, cbB, d_out, flag);
}